// Round 12
// baseline (129.403 us; speedup 1.0000x reference)
//
#include <hip/hip_runtime.h>
#include <hip/hip_bf16.h>
#include <stdint.h>

// AttentionBlock: GN(8) -> qkv 1x1 -> attention(1024 tok, d=256) -> proj -> +x
// b=32, c=256, h=w=32 (hw=1024). fp32 in/out; bf16 MFMA internally.

typedef __bf16 bf16_t;
typedef __bf16 bf16x4 __attribute__((ext_vector_type(4)));
typedef __bf16 bf16x8 __attribute__((ext_vector_type(8)));
typedef float f32x4 __attribute__((ext_vector_type(4)));
typedef float f32x16 __attribute__((ext_vector_type(16)));
typedef _Float16 f16x4 __attribute__((ext_vector_type(4)));

#define MFMA32(a, b, c) __builtin_amdgcn_mfma_f32_32x32x16_bf16((a), (b), (c), 0, 0, 0)
#define MFMA16(a, b, c) __builtin_amdgcn_mfma_f32_16x16x32_bf16((a), (b), (c), 0, 0, 0)
#define GLL16(g, l)                                                                      \
    __builtin_amdgcn_global_load_lds((const __attribute__((address_space(1))) void*)(g), \
                                     (__attribute__((address_space(3))) void*)(l), 16, 0, 0)
#define WAITV0 asm volatile("s_waitcnt vmcnt(0)" ::: "memory")
#define SBAR   __builtin_amdgcn_s_barrier()

// Q pre-scale: (1/sqrt(256)) * log2(e)  -> softmax in exp2 domain
#define QSCALE 0.0901684400555f

// ---------------- K0: fp32 -> bf16 cast (both weight tensors, one launch) ----------
__global__ void cast_w(const float* __restrict__ s1, bf16_t* __restrict__ d1, int n1,
                       const float* __restrict__ s2, bf16_t* __restrict__ d2, int n2) {
    int i = blockIdx.x * blockDim.x + threadIdx.x;
    int stride = gridDim.x * blockDim.x;
    for (int k = i; k < n1; k += stride) d1[k] = (bf16_t)s1[k];
    for (int k = i; k < n2; k += stride) d2[k] = (bf16_t)s2[k];
}

// ---------------- K1: GroupNorm + transpose to (b, pixel, c) bf16 ----------------
__global__ __launch_bounds__(512) void gn_kernel(const float* __restrict__ x,
                                                 const float* __restrict__ gamma,
                                                 const float* __restrict__ beta,
                                                 bf16_t* __restrict__ xn) {
    extern __shared__ char gsm[];  // 65536 (fp16 stash) + 64 (reduce)
    float* red = (float*)(gsm + 65536);
    int bg = blockIdx.x, b = bg >> 3, g = bg & 7;
    const float* base = x + (size_t)(b * 256 + g * 32) * 1024;
    int tid = threadIdx.x;
    int half = tid >> 8, col = tid & 255;

    float s = 0.f, ss = 0.f;
    #pragma unroll 4
    for (int c2 = 0; c2 < 16; c2++) {
        int c = c2 * 2 + half;
        float4 v = *(const float4*)(base + c * 1024 + col * 4);
        s += v.x + v.y + v.z + v.w;
        ss += v.x * v.x + v.y * v.y + v.z * v.z + v.w * v.w;
        f16x4 h = {(_Float16)v.x, (_Float16)v.y, (_Float16)v.z, (_Float16)v.w};
        *(f16x4*)(gsm + c * 2048 + ((col * 8) ^ ((c & 7) << 4))) = h;
    }
    for (int off = 32; off; off >>= 1) { s += __shfl_down(s, off); ss += __shfl_down(ss, off); }
    if ((tid & 63) == 0) { red[tid >> 6] = s; red[8 + (tid >> 6)] = ss; }
    __syncthreads();
    float S = 0.f, SS = 0.f;
    #pragma unroll
    for (int k = 0; k < 8; k++) { S += red[k]; SS += red[8 + k]; }
    float mean = S * (1.0f / 32768.0f);
    float var = SS * (1.0f / 32768.0f) - mean * mean;
    float rstd = rsqrtf(var + 1e-5f);

    int c = tid & 31;
    float gam = gamma[g * 32 + c] * rstd;
    float bet = beta[g * 32 + c] - mean * gam;
    bf16_t* dst = xn + (size_t)(b * 1024) * 256 + g * 32 + c;
    #pragma unroll 4
    for (int it = 0; it < 64; it++) {
        int p = it * 16 + (tid >> 5);
        _Float16 hv = *(_Float16*)(gsm + c * 2048 + ((p * 2) ^ ((c & 7) << 4)));
        dst[(size_t)p * 256] = (bf16_t)((float)hv * gam + bet);
    }
}

// ---------------- K2: merged QKV GEMM — 512 threads, 8 wave-tiles of 32x32 --------
__global__ __launch_bounds__(512, 2) void gemm_qkv(const bf16_t* __restrict__ xn,
                                                   const bf16_t* __restrict__ wq,
                                                   const float* __restrict__ qkv_b,
                                                   bf16_t* __restrict__ qb,
                                                   bf16_t* __restrict__ kb,
                                                   bf16_t* __restrict__ vt) {
    extern __shared__ char smem[];  // As 64KB | B dbuf 2x32KB
    char* As = smem;
    int tid = threadIdx.x, wv = tid >> 6, lane = tid & 63;
    int l31 = lane & 31, hi = lane >> 5;
    int t0 = blockIdx.x * 128;
    const char* asrc = (const char*)xn + (size_t)t0 * 512;
    const char* wsrc = (const char*)wq;

    {
        int u = lane & 31, rofs = lane >> 5;
        #pragma unroll
        for (int t = 0; t < 8; t++) {
            int r0 = wv * 16 + t * 2;
            int r = r0 + rofs;
            GLL16(asrc + (size_t)r * 512 + ((u ^ (r & 31)) * 16), As + r0 * 512);
        }
    }
    auto stage_B = [&](int nt) {
        char* Bd = smem + 65536 + (nt & 1) * 32768;
        int u = lane & 31, rofs = lane >> 5;
        #pragma unroll
        for (int t = 0; t < 4; t++) {
            int r0 = wv * 8 + t * 2;
            int r = r0 + rofs;
            GLL16(wsrc + (size_t)(nt * 64 + r) * 512 + ((u ^ (r & 31)) * 16), Bd + r0 * 512);
        }
    };
    stage_B(0);
    WAITV0; SBAR;

    int wm = wv >> 1, wd = wv & 1;
    int bb = t0 >> 10, pos0 = t0 & 1023;

    for (int nt = 0; nt < 12; nt++) {
        if (nt < 11) stage_B(nt + 1);
        const char* Bs = smem + 65536 + (nt & 1) * 32768;
        f32x16 acc = {};
        if (nt < 8) {
            __builtin_amdgcn_s_setprio(1);
            #pragma unroll
            for (int ks = 0; ks < 16; ks++) {
                int col = ks * 32 + hi * 16;
                bf16x8 a = *(const bf16x8*)(As + (wm * 32 + l31) * 512 + (col ^ (l31 << 4)));
                bf16x8 bfr = *(const bf16x8*)(Bs + (wd * 32 + l31) * 512 + (col ^ (l31 << 4)));
                acc = MFMA32(a, bfr, acc);
            }
            __builtin_amdgcn_s_setprio(0);
            int d = nt * 64 + wd * 32 + l31;
            bool isq = nt < 4;
            float bias = qkv_b[d];
            bf16_t* dst = isq ? qb : kb;
            int dd = isq ? d : d - 256;
            float sc = isq ? QSCALE : 1.0f;
            #pragma unroll
            for (int r = 0; r < 16; r++) {
                int tok = t0 + wm * 32 + (r & 3) + 8 * (r >> 2) + 4 * hi;
                dst[(size_t)tok * 256 + dd] = (bf16_t)((acc[r] + bias) * sc);
            }
        } else {
            __builtin_amdgcn_s_setprio(1);
            #pragma unroll
            for (int ks = 0; ks < 16; ks++) {
                int col = ks * 32 + hi * 16;
                bf16x8 a = *(const bf16x8*)(As + (wm * 32 + l31) * 512 + (col ^ (l31 << 4)));
                bf16x8 bfr = *(const bf16x8*)(Bs + (wd * 32 + l31) * 512 + (col ^ (l31 << 4)));
                acc = MFMA32(bfr, a, acc);  // swapped: D[d][tok]
            }
            __builtin_amdgcn_s_setprio(0);
            int dbase = (nt - 8) * 64 + wd * 32;
            int pos = pos0 + wm * 32 + l31;
            #pragma unroll
            for (int r = 0; r < 16; r++) {
                int d = dbase + (r & 3) + 8 * (r >> 2) + 4 * hi;
                vt[(size_t)bb * 262144 + (size_t)d * 1024 + pos] =
                    (bf16_t)(acc[r] + qkv_b[512 + d]);
            }
        }
        if (nt < 11) { WAITV0; SBAR; }
    }
}

// ---------------- K3: fused attention — 16-q waves, 2 blocks/CU, 2 waves/SIMD -----
// grid 512 = (b, 16 q-tiles of 64). 4 waves x 16 q-rows, full d=256 per wave.
// Tk=32 double-buffered: K 2x16KB (32 rows x 512B, key ((r&7)<<2)^(r>>3)) +
// V 2x16KB (256 d-rows x 64B, within-row key (d>>3)&3) + P 4x1KB = 68KB LDS.
// mfma_f32_16x16x32_bf16 throughout; swapped QK^T; per-wave LDS-P; exp2 softmax.
__global__ __launch_bounds__(256, 2) void attn_kernel(const bf16_t* __restrict__ qb,
                                                      const bf16_t* __restrict__ kb,
                                                      const bf16_t* __restrict__ vt,
                                                      bf16_t* __restrict__ ao) {
    extern __shared__ char smem[];  // K dbuf 2x16KB @0 | V dbuf 2x16KB @32768 | P @65536
    int tid = threadIdx.x, i = blockIdx.x;
    int b = (i & 7) + ((i >> 7) << 3);   // 16 blocks of each batch share an XCD
    int qt = (i >> 3) & 15;
    int wv = tid >> 6, lane = tid & 63;
    int q15 = lane & 15, g = lane >> 4;

    const char* kbase = (const char*)kb + (size_t)b * 524288;
    const char* vbase = (const char*)vt + (size_t)b * 524288;
    char* Pw = smem + 65536 + wv * 1024;

    int qrow = qt * 64 + wv * 16 + q15;
    const char* qsrc = (const char*)qb + (size_t)(b * 1024 + qrow) * 512;
    bf16x8 qf[8];
    #pragma unroll
    for (int f = 0; f < 8; f++) qf[f] = *(const bf16x8*)(qsrc + f * 64 + g * 16);

    f32x4 o16[16] = {};
    float mrun = -1e30f, lrun = 0.f;

    // stage chunk ch (32 keys) into buffer ch&1; linear LDS dest, pre-swizzled src
    auto stage = [&](int ch) {
        char* Kd = smem + (ch & 1) * 16384;
        char* Vd = smem + 32768 + (ch & 1) * 16384;
        int j0 = ch * 32;
        #pragma unroll
        for (int p = 0; p < 4; p++) {  // K: 32 rows x 512B
            int Ls = tid * 16 + p * 4096;
            int r = Ls >> 9, u = (Ls >> 4) & 31;
            int fk = ((r & 7) << 2) ^ (r >> 3);
            GLL16(kbase + (size_t)(j0 + r) * 512 + ((u ^ fk) << 4),
                  Kd + p * 4096 + wv * 1024);
        }
        #pragma unroll
        for (int p = 0; p < 4; p++) {  // V^T: 256 d-rows x 64B
            int Ls = tid * 16 + p * 4096;
            int d = Ls >> 6, u2 = (Ls >> 4) & 3;
            GLL16(vbase + (size_t)d * 2048 + j0 * 2 + ((u2 ^ ((d >> 3) & 3)) << 4),
                  Vd + p * 4096 + wv * 1024);
        }
    };

    stage(0);
    __syncthreads();

    int fk0 = ((q15 & 7) << 2) ^ (q15 >> 3);       // key for K row q15 (kt=0)
    int kr1 = 16 + q15;
    int fk1 = ((kr1 & 7) << 2) ^ (kr1 >> 3);       // key for K row 16+q15 (kt=1)

    for (int ch = 0; ch < 32; ch++) {
        const char* Ks = smem + (ch & 1) * 16384;
        const char* Vs = smem + 32768 + (ch & 1) * 16384;
        if (ch < 31) stage(ch + 1);

        // S^T[k][q] = K·Q^T : A = K-tile rows, B = Q (regs). kt=0 -> sv0, kt=1 -> sv1
        f32x4 sv0 = {}, sv1 = {};
        #pragma unroll
        for (int f = 0; f < 8; f++) {
            int c = f * 4 + g;
            bf16x8 k0 = *(const bf16x8*)(Ks + q15 * 512 + ((c ^ fk0) << 4));
            bf16x8 k1 = *(const bf16x8*)(Ks + kr1 * 512 + ((c ^ fk1) << 4));
            sv0 = MFMA16(k0, qf[f], sv0);
            sv1 = MFMA16(k1, qf[f], sv1);
        }

        // online softmax over 32 keys: lane holds k = 4g+r (sv0), 16+4g+r (sv1), q=q15
        float mc = fmaxf(fmaxf(fmaxf(sv0[0], sv0[1]), fmaxf(sv0[2], sv0[3])),
                         fmaxf(fmaxf(sv1[0], sv1[1]), fmaxf(sv1[2], sv1[3])));
        mc = fmaxf(mc, __shfl_xor(mc, 16));
        mc = fmaxf(mc, __shfl_xor(mc, 32));
        float mo = mrun;
        float mn = (mc <= mo + 8.0f) ? mo : mc;
        float rs = 0.f;
        #pragma unroll
        for (int r = 0; r < 4; r++) {
            sv0[r] = exp2f(sv0[r] - mn);
            sv1[r] = exp2f(sv1[r] - mn);
            rs += sv0[r] + sv1[r];
        }
        rs += __shfl_xor(rs, 16);
        rs += __shfl_xor(rs, 32);
        float al = exp2f(mo - mn);
        lrun = lrun * al + rs;
        mrun = mn;

        // P[q][k] -> per-wave LDS (row q = 64B, 16B-block key q&3)
        bf16x4 pa, pb;
        #pragma unroll
        for (int r = 0; r < 4; r++) { pa[r] = (bf16_t)sv0[r]; pb[r] = (bf16_t)sv1[r]; }
        int blk0 = (g >> 1) ^ (q15 & 3);
        int blk1 = ((g >> 1) + 2) ^ (q15 & 3);
        *(bf16x4*)(Pw + q15 * 64 + blk0 * 16 + (g & 1) * 8) = pa;
        *(bf16x4*)(Pw + q15 * 64 + blk1 * 16 + (g & 1) * 8) = pb;
        if (__any(mn != mo)) {
            #pragma unroll
            for (int dt = 0; dt < 16; dt++) o16[dt] = o16[dt] * al;
        }

        // O^T[d][q] += V^T·P^T : A = V^T d-rows, B = P (k=32 in one MFMA)
        bf16x8 pf = *(const bf16x8*)(Pw + q15 * 64 + ((g ^ (q15 & 3)) << 4));
        #pragma unroll
        for (int dt = 0; dt < 16; dt++) {
            int d = dt * 16 + q15;
            bf16x8 vf = *(const bf16x8*)(Vs + d * 64 + ((g ^ ((d >> 3) & 3)) << 4));
            o16[dt] = MFMA16(vf, pf, o16[dt]);
        }
        __syncthreads();  // stage(ch+1) drained; all reads of cur buffer done
    }

    float inv = 1.0f / lrun;
    char* aod = (char*)ao + (size_t)(b * 1024 + qrow) * 512;
    #pragma unroll
    for (int dt = 0; dt < 16; dt++) {
        bf16x4 w;
        #pragma unroll
        for (int r = 0; r < 4; r++) w[r] = (bf16_t)(o16[dt][r] * inv);
        *(bf16x4*)(aod + dt * 32 + g * 8) = w;
    }
}

// ---------------- K4: out-proj GEMM + bias + residual — 512 threads ---------------
__global__ __launch_bounds__(512, 2) void gemm_out(const bf16_t* __restrict__ wo,
                                                   const bf16_t* __restrict__ ao,
                                                   const float* __restrict__ out_b,
                                                   const float* __restrict__ x,
                                                   float* __restrict__ out) {
    extern __shared__ char smem[];  // Bs(ao) 64KB | W dbuf 2x32KB
    char* Bs = smem;
    int tid = threadIdx.x, wv = tid >> 6, lane = tid & 63;
    int l31 = lane & 31, hi = lane >> 5;
    int t0 = blockIdx.x * 128;
    const char* bsrc = (const char*)ao + (size_t)t0 * 512;
    const char* wsrc = (const char*)wo;

    {
        int u = lane & 31, rofs = lane >> 5;
        #pragma unroll
        for (int t = 0; t < 8; t++) {
            int r0 = wv * 16 + t * 2;
            int r = r0 + rofs;
            GLL16(bsrc + (size_t)r * 512 + ((u ^ (r & 31)) * 16), Bs + r0 * 512);
        }
    }
    auto stage_W = [&](int ct) {
        char* Wd = smem + 65536 + (ct & 1) * 32768;
        int u = lane & 31, rofs = lane >> 5;
        #pragma unroll
        for (int t = 0; t < 4; t++) {
            int r0 = wv * 8 + t * 2;
            int r = r0 + rofs;
            GLL16(wsrc + (size_t)(ct * 64 + r) * 512 + ((u ^ (r & 31)) * 16), Wd + r0 * 512);
        }
    };
    stage_W(0);
    WAITV0; SBAR;

    int wm = wv >> 1, wc = wv & 1;
    int bb = t0 >> 10, pos0 = t0 & 1023;

    for (int ct = 0; ct < 4; ct++) {
        if (ct < 3) stage_W(ct + 1);
        const char* Ws = smem + 65536 + (ct & 1) * 32768;
        f32x16 acc = {};
        __builtin_amdgcn_s_setprio(1);
        #pragma unroll
        for (int ks = 0; ks < 16; ks++) {
            int col = ks * 32 + hi * 16;
            bf16x8 w = *(const bf16x8*)(Ws + (wc * 32 + l31) * 512 + (col ^ (l31 << 4)));
            bf16x8 bf = *(const bf16x8*)(Bs + (wm * 32 + l31) * 512 + (col ^ (l31 << 4)));
            acc = MFMA32(w, bf, acc);
        }
        __builtin_amdgcn_s_setprio(0);
        int pos = pos0 + wm * 32 + l31;
        #pragma unroll
        for (int r = 0; r < 16; r++) {
            int c = ct * 64 + wc * 32 + (r & 3) + 8 * (r >> 2) + 4 * hi;
            size_t idx = ((size_t)bb * 256 + c) * 1024 + pos;
            out[idx] = acc[r] + out_b[c] + x[idx];
        }
        if (ct < 3) { WAITV0; SBAR; }
    }
}

// ---------------- launcher ----------------
extern "C" void kernel_launch(void* const* d_in, const int* in_sizes, int n_in,
                              void* d_out, int out_size, void* d_ws, size_t ws_size,
                              hipStream_t stream) {
    (void)in_sizes; (void)n_in; (void)out_size; (void)ws_size;
    const float* x      = (const float*)d_in[0];
    const float* gamma  = (const float*)d_in[1];
    const float* beta   = (const float*)d_in[2];
    const float* qkv_w  = (const float*)d_in[3];
    const float* qkv_b  = (const float*)d_in[4];
    const float* out_w  = (const float*)d_in[5];
    const float* out_b  = (const float*)d_in[6];
    float* out = (float*)d_out;

    char* ws = (char*)d_ws;
    const size_t MB16 = 16777216;
    bf16_t* xn  = (bf16_t*)(ws);             // (b, n, 256) bf16
    bf16_t* qb  = (bf16_t*)(ws + 1 * MB16);  // (b, n, 256)  pre-scaled by QSCALE
    bf16_t* kb  = (bf16_t*)(ws + 2 * MB16);  // (b, n, 256)
    bf16_t* vt  = (bf16_t*)(ws + 3 * MB16);  // (b, 256, n)  V transposed
    bf16_t* ao  = (bf16_t*)(ws + 4 * MB16);  // (b, n, 256)
    bf16_t* wqb = (bf16_t*)(ws + 5 * MB16);            // 768x256 bf16
    bf16_t* wob = (bf16_t*)(ws + 5 * MB16 + 393216);   // 256x256 bf16

    cast_w<<<256, 256, 0, stream>>>(qkv_w, wqb, 196608, out_w, wob, 65536);
    gn_kernel<<<256, 512, 65600, stream>>>(x, gamma, beta, xn);
    gemm_qkv<<<256, 512, 131072, stream>>>(xn, wqb, qkv_b, qb, kb, vt);
    attn_kernel<<<512, 256, 69632, stream>>>(qb, kb, vt, ao);
    gemm_out<<<256, 512, 131072, stream>>>(wob, ao, out_b, x, out);
}

// Round 13
// 127.091 us; speedup vs baseline: 1.0182x; 1.0182x over previous
//
#include <hip/hip_runtime.h>
#include <hip/hip_bf16.h>
#include <stdint.h>

// AttentionBlock: GN(8) -> qkv 1x1 -> attention(1024 tok, d=256) -> proj -> +x
// b=32, c=256, h=w=32 (hw=1024). fp32 in/out; bf16 MFMA internally.

typedef __bf16 bf16_t;
typedef __bf16 bf16x4 __attribute__((ext_vector_type(4)));
typedef __bf16 bf16x8 __attribute__((ext_vector_type(8)));
typedef float f32x4 __attribute__((ext_vector_type(4)));
typedef float f32x16 __attribute__((ext_vector_type(16)));
typedef _Float16 f16x4 __attribute__((ext_vector_type(4)));

#define MFMA32(a, b, c) __builtin_amdgcn_mfma_f32_32x32x16_bf16((a), (b), (c), 0, 0, 0)
#define MFMA16(a, b, c) __builtin_amdgcn_mfma_f32_16x16x32_bf16((a), (b), (c), 0, 0, 0)
#define GLL16(g, l)                                                                      \
    __builtin_amdgcn_global_load_lds((const __attribute__((address_space(1))) void*)(g), \
                                     (__attribute__((address_space(3))) void*)(l), 16, 0, 0)
#define WAITV0 asm volatile("s_waitcnt vmcnt(0)" ::: "memory")
#define SBAR   __builtin_amdgcn_s_barrier()

// Q pre-scale: (1/sqrt(256)) * log2(e)  -> softmax in exp2 domain
#define QSCALE 0.0901684400555f

// ---------------- K0: fp32 -> bf16 cast (both weight tensors, one launch) ----------
__global__ void cast_w(const float* __restrict__ s1, bf16_t* __restrict__ d1, int n1,
                       const float* __restrict__ s2, bf16_t* __restrict__ d2, int n2) {
    int i = blockIdx.x * blockDim.x + threadIdx.x;
    int stride = gridDim.x * blockDim.x;
    for (int k = i; k < n1; k += stride) d1[k] = (bf16_t)s1[k];
    for (int k = i; k < n2; k += stride) d2[k] = (bf16_t)s2[k];
}

// ---------------- K1: GroupNorm + transpose to (b, pixel, c) bf16 ----------------
__global__ __launch_bounds__(512) void gn_kernel(const float* __restrict__ x,
                                                 const float* __restrict__ gamma,
                                                 const float* __restrict__ beta,
                                                 bf16_t* __restrict__ xn) {
    extern __shared__ char gsm[];  // 65536 (fp16 stash) + 64 (reduce)
    float* red = (float*)(gsm + 65536);
    int bg = blockIdx.x, b = bg >> 3, g = bg & 7;
    const float* base = x + (size_t)(b * 256 + g * 32) * 1024;
    int tid = threadIdx.x;
    int half = tid >> 8, col = tid & 255;

    float s = 0.f, ss = 0.f;
    #pragma unroll 4
    for (int c2 = 0; c2 < 16; c2++) {
        int c = c2 * 2 + half;
        float4 v = *(const float4*)(base + c * 1024 + col * 4);
        s += v.x + v.y + v.z + v.w;
        ss += v.x * v.x + v.y * v.y + v.z * v.z + v.w * v.w;
        f16x4 h = {(_Float16)v.x, (_Float16)v.y, (_Float16)v.z, (_Float16)v.w};
        *(f16x4*)(gsm + c * 2048 + ((col * 8) ^ ((c & 7) << 4))) = h;
    }
    for (int off = 32; off; off >>= 1) { s += __shfl_down(s, off); ss += __shfl_down(ss, off); }
    if ((tid & 63) == 0) { red[tid >> 6] = s; red[8 + (tid >> 6)] = ss; }
    __syncthreads();
    float S = 0.f, SS = 0.f;
    #pragma unroll
    for (int k = 0; k < 8; k++) { S += red[k]; SS += red[8 + k]; }
    float mean = S * (1.0f / 32768.0f);
    float var = SS * (1.0f / 32768.0f) - mean * mean;
    float rstd = rsqrtf(var + 1e-5f);

    int c = tid & 31;
    float gam = gamma[g * 32 + c] * rstd;
    float bet = beta[g * 32 + c] - mean * gam;
    bf16_t* dst = xn + (size_t)(b * 1024) * 256 + g * 32 + c;
    #pragma unroll 4
    for (int it = 0; it < 64; it++) {
        int p = it * 16 + (tid >> 5);
        _Float16 hv = *(_Float16*)(gsm + c * 2048 + ((p * 2) ^ ((c & 7) << 4)));
        dst[(size_t)p * 256] = (bf16_t)((float)hv * gam + bet);
    }
}

// ---------------- K2: merged QKV GEMM — 512 threads, 8 wave-tiles of 32x32 --------
__global__ __launch_bounds__(512, 2) void gemm_qkv(const bf16_t* __restrict__ xn,
                                                   const bf16_t* __restrict__ wq,
                                                   const float* __restrict__ qkv_b,
                                                   bf16_t* __restrict__ qb,
                                                   bf16_t* __restrict__ kb,
                                                   bf16_t* __restrict__ vt) {
    extern __shared__ char smem[];  // As 64KB | B dbuf 2x32KB
    char* As = smem;
    int tid = threadIdx.x, wv = tid >> 6, lane = tid & 63;
    int l31 = lane & 31, hi = lane >> 5;
    int t0 = blockIdx.x * 128;
    const char* asrc = (const char*)xn + (size_t)t0 * 512;
    const char* wsrc = (const char*)wq;

    {
        int u = lane & 31, rofs = lane >> 5;
        #pragma unroll
        for (int t = 0; t < 8; t++) {
            int r0 = wv * 16 + t * 2;
            int r = r0 + rofs;
            GLL16(asrc + (size_t)r * 512 + ((u ^ (r & 31)) * 16), As + r0 * 512);
        }
    }
    auto stage_B = [&](int nt) {
        char* Bd = smem + 65536 + (nt & 1) * 32768;
        int u = lane & 31, rofs = lane >> 5;
        #pragma unroll
        for (int t = 0; t < 4; t++) {
            int r0 = wv * 8 + t * 2;
            int r = r0 + rofs;
            GLL16(wsrc + (size_t)(nt * 64 + r) * 512 + ((u ^ (r & 31)) * 16), Bd + r0 * 512);
        }
    };
    stage_B(0);
    WAITV0; SBAR;

    int wm = wv >> 1, wd = wv & 1;
    int bb = t0 >> 10, pos0 = t0 & 1023;

    for (int nt = 0; nt < 12; nt++) {
        if (nt < 11) stage_B(nt + 1);
        const char* Bs = smem + 65536 + (nt & 1) * 32768;
        f32x16 acc = {};
        if (nt < 8) {
            __builtin_amdgcn_s_setprio(1);
            #pragma unroll
            for (int ks = 0; ks < 16; ks++) {
                int col = ks * 32 + hi * 16;
                bf16x8 a = *(const bf16x8*)(As + (wm * 32 + l31) * 512 + (col ^ (l31 << 4)));
                bf16x8 bfr = *(const bf16x8*)(Bs + (wd * 32 + l31) * 512 + (col ^ (l31 << 4)));
                acc = MFMA32(a, bfr, acc);
            }
            __builtin_amdgcn_s_setprio(0);
            int d = nt * 64 + wd * 32 + l31;
            bool isq = nt < 4;
            float bias = qkv_b[d];
            bf16_t* dst = isq ? qb : kb;
            int dd = isq ? d : d - 256;
            float sc = isq ? QSCALE : 1.0f;
            #pragma unroll
            for (int r = 0; r < 16; r++) {
                int tok = t0 + wm * 32 + (r & 3) + 8 * (r >> 2) + 4 * hi;
                dst[(size_t)tok * 256 + dd] = (bf16_t)((acc[r] + bias) * sc);
            }
        } else {
            __builtin_amdgcn_s_setprio(1);
            #pragma unroll
            for (int ks = 0; ks < 16; ks++) {
                int col = ks * 32 + hi * 16;
                bf16x8 a = *(const bf16x8*)(As + (wm * 32 + l31) * 512 + (col ^ (l31 << 4)));
                bf16x8 bfr = *(const bf16x8*)(Bs + (wd * 32 + l31) * 512 + (col ^ (l31 << 4)));
                acc = MFMA32(bfr, a, acc);  // swapped: D[d][tok]
            }
            __builtin_amdgcn_s_setprio(0);
            int dbase = (nt - 8) * 64 + wd * 32;
            int pos = pos0 + wm * 32 + l31;
            #pragma unroll
            for (int r = 0; r < 16; r++) {
                int d = dbase + (r & 3) + 8 * (r >> 2) + 4 * hi;
                vt[(size_t)bb * 262144 + (size_t)d * 1024 + pos] =
                    (bf16_t)(acc[r] + qkv_b[512 + d]);
            }
        }
        if (nt < 11) { WAITV0; SBAR; }
    }
}

// ---------------- K3: fused attention — 16-q waves, 2 blocks/CU, fixed swizzles ----
// grid 512 = (b, 16 q-tiles of 64). 4 waves x 16 q-rows, full d=256 per wave.
// Tk=32 dbuf: K 2x16KB (32 rows x 512B, key = r full 5-bit) + V 2x16KB (256 d-rows
// x 64B, key (d>>1)&3) + P 4x1KB (key (q15>>1)&3) = 68KB LDS -> 2 blocks/CU.
// All keys inject q15 bits 1-2 into the bank-group (2-way at 16-lane phase level).
__global__ __launch_bounds__(256, 2) void attn_kernel(const bf16_t* __restrict__ qb,
                                                      const bf16_t* __restrict__ kb,
                                                      const bf16_t* __restrict__ vt,
                                                      bf16_t* __restrict__ ao) {
    extern __shared__ char smem[];  // K dbuf 2x16KB @0 | V dbuf 2x16KB @32768 | P @65536
    int tid = threadIdx.x, i = blockIdx.x;
    int b = (i & 7) + ((i >> 7) << 3);   // 16 blocks of each batch share an XCD
    int qt = (i >> 3) & 15;
    int wv = tid >> 6, lane = tid & 63;
    int q15 = lane & 15, g = lane >> 4;

    const char* kbase = (const char*)kb + (size_t)b * 524288;
    const char* vbase = (const char*)vt + (size_t)b * 524288;
    char* Pw = smem + 65536 + wv * 1024;

    int qrow = qt * 64 + wv * 16 + q15;
    const char* qsrc = (const char*)qb + (size_t)(b * 1024 + qrow) * 512;
    bf16x8 qf[8];
    #pragma unroll
    for (int f = 0; f < 8; f++) qf[f] = *(const bf16x8*)(qsrc + f * 64 + g * 16);

    f32x4 o16[16] = {};
    float mrun = -1e30f, lrun = 0.f;

    // stage chunk ch (32 keys) into buffer ch&1; linear LDS dest, pre-swizzled src
    auto stage = [&](int ch) {
        char* Kd = smem + (ch & 1) * 16384;
        char* Vd = smem + 32768 + (ch & 1) * 16384;
        int j0 = ch * 32;
        #pragma unroll
        for (int p = 0; p < 4; p++) {  // K: 32 rows x 512B, key = r (full 5-bit)
            int Ls = tid * 16 + p * 4096;
            int r = Ls >> 9, u = (Ls >> 4) & 31;
            GLL16(kbase + (size_t)(j0 + r) * 512 + ((u ^ r) << 4),
                  Kd + p * 4096 + wv * 1024);
        }
        #pragma unroll
        for (int p = 0; p < 4; p++) {  // V^T: 256 d-rows x 64B, key (d>>1)&3
            int Ls = tid * 16 + p * 4096;
            int d = Ls >> 6, u2 = (Ls >> 4) & 3;
            GLL16(vbase + (size_t)d * 2048 + j0 * 2 + ((u2 ^ ((d >> 1) & 3)) << 4),
                  Vd + p * 4096 + wv * 1024);
        }
    };

    stage(0);
    __syncthreads();

    int kr1 = 16 + q15;
    int kp = (q15 >> 1) & 3;  // P swizzle key

    for (int ch = 0; ch < 32; ch++) {
        const char* Ks = smem + (ch & 1) * 16384;
        const char* Vs = smem + 32768 + (ch & 1) * 16384;
        if (ch < 31) stage(ch + 1);

        // S^T[k][q] = K·Q^T : A = K-tile rows, B = Q (regs). kt=0 -> sv0, kt=1 -> sv1
        f32x4 sv0 = {}, sv1 = {};
        #pragma unroll
        for (int f = 0; f < 8; f++) {
            int c = f * 4 + g;
            bf16x8 k0 = *(const bf16x8*)(Ks + q15 * 512 + ((c ^ q15) << 4));
            bf16x8 k1 = *(const bf16x8*)(Ks + kr1 * 512 + ((c ^ kr1) << 4));
            sv0 = MFMA16(k0, qf[f], sv0);
            sv1 = MFMA16(k1, qf[f], sv1);
        }

        // online softmax over 32 keys: lane holds k = 4g+r (sv0), 16+4g+r (sv1), q=q15
        float mc = fmaxf(fmaxf(fmaxf(sv0[0], sv0[1]), fmaxf(sv0[2], sv0[3])),
                         fmaxf(fmaxf(sv1[0], sv1[1]), fmaxf(sv1[2], sv1[3])));
        mc = fmaxf(mc, __shfl_xor(mc, 16));
        mc = fmaxf(mc, __shfl_xor(mc, 32));
        float mo = mrun;
        float mn = (mc <= mo + 8.0f) ? mo : mc;
        float rs = 0.f;
        #pragma unroll
        for (int r = 0; r < 4; r++) {
            sv0[r] = exp2f(sv0[r] - mn);
            sv1[r] = exp2f(sv1[r] - mn);
            rs += sv0[r] + sv1[r];
        }
        rs += __shfl_xor(rs, 16);
        rs += __shfl_xor(rs, 32);
        float al = exp2f(mo - mn);
        lrun = lrun * al + rs;
        mrun = mn;

        // P[q][k] -> per-wave LDS (row q = 64B, 16B-block key (q15>>1)&3)
        bf16x4 pa, pb;
        #pragma unroll
        for (int r = 0; r < 4; r++) { pa[r] = (bf16_t)sv0[r]; pb[r] = (bf16_t)sv1[r]; }
        int blk0 = (g >> 1) ^ kp;
        int blk1 = (2 + (g >> 1)) ^ kp;
        *(bf16x4*)(Pw + q15 * 64 + blk0 * 16 + (g & 1) * 8) = pa;
        *(bf16x4*)(Pw + q15 * 64 + blk1 * 16 + (g & 1) * 8) = pb;
        if (__any(mn != mo)) {
            #pragma unroll
            for (int dt = 0; dt < 16; dt++) o16[dt] = o16[dt] * al;
        }

        // O^T[d][q] += V^T·P^T : A = V^T d-rows, B = P (k=32 in one MFMA)
        bf16x8 pf = *(const bf16x8*)(Pw + q15 * 64 + ((g ^ kp) << 4));
        #pragma unroll
        for (int dt = 0; dt < 16; dt++) {
            int d = dt * 16 + q15;
            bf16x8 vf = *(const bf16x8*)(Vs + d * 64 + ((g ^ ((d >> 1) & 3)) << 4));
            o16[dt] = MFMA16(vf, pf, o16[dt]);
        }
        __syncthreads();  // stage(ch+1) drained; all reads of cur buffer done
    }

    float inv = 1.0f / lrun;
    char* aod = (char*)ao + (size_t)(b * 1024 + qrow) * 512;
    #pragma unroll
    for (int dt = 0; dt < 16; dt++) {
        bf16x4 w;
        #pragma unroll
        for (int r = 0; r < 4; r++) w[r] = (bf16_t)(o16[dt][r] * inv);
        *(bf16x4*)(aod + dt * 32 + g * 8) = w;
    }
}

// ---------------- K4: out-proj GEMM + bias + residual — 512 threads ---------------
__global__ __launch_bounds__(512, 2) void gemm_out(const bf16_t* __restrict__ wo,
                                                   const bf16_t* __restrict__ ao,
                                                   const float* __restrict__ out_b,
                                                   const float* __restrict__ x,
                                                   float* __restrict__ out) {
    extern __shared__ char smem[];  // Bs(ao) 64KB | W dbuf 2x32KB
    char* Bs = smem;
    int tid = threadIdx.x, wv = tid >> 6, lane = tid & 63;
    int l31 = lane & 31, hi = lane >> 5;
    int t0 = blockIdx.x * 128;
    const char* bsrc = (const char*)ao + (size_t)t0 * 512;
    const char* wsrc = (const char*)wo;

    {
        int u = lane & 31, rofs = lane >> 5;
        #pragma unroll
        for (int t = 0; t < 8; t++) {
            int r0 = wv * 16 + t * 2;
            int r = r0 + rofs;
            GLL16(bsrc + (size_t)r * 512 + ((u ^ (r & 31)) * 16), Bs + r0 * 512);
        }
    }
    auto stage_W = [&](int ct) {
        char* Wd = smem + 65536 + (ct & 1) * 32768;
        int u = lane & 31, rofs = lane >> 5;
        #pragma unroll
        for (int t = 0; t < 4; t++) {
            int r0 = wv * 8 + t * 2;
            int r = r0 + rofs;
            GLL16(wsrc + (size_t)(ct * 64 + r) * 512 + ((u ^ (r & 31)) * 16), Wd + r0 * 512);
        }
    };
    stage_W(0);
    WAITV0; SBAR;

    int wm = wv >> 1, wc = wv & 1;
    int bb = t0 >> 10, pos0 = t0 & 1023;

    for (int ct = 0; ct < 4; ct++) {
        if (ct < 3) stage_W(ct + 1);
        const char* Ws = smem + 65536 + (ct & 1) * 32768;
        f32x16 acc = {};
        __builtin_amdgcn_s_setprio(1);
        #pragma unroll
        for (int ks = 0; ks < 16; ks++) {
            int col = ks * 32 + hi * 16;
            bf16x8 w = *(const bf16x8*)(Ws + (wc * 32 + l31) * 512 + (col ^ (l31 << 4)));
            bf16x8 bf = *(const bf16x8*)(Bs + (wm * 32 + l31) * 512 + (col ^ (l31 << 4)));
            acc = MFMA32(w, bf, acc);
        }
        __builtin_amdgcn_s_setprio(0);
        int pos = pos0 + wm * 32 + l31;
        #pragma unroll
        for (int r = 0; r < 16; r++) {
            int c = ct * 64 + wc * 32 + (r & 3) + 8 * (r >> 2) + 4 * hi;
            size_t idx = ((size_t)bb * 256 + c) * 1024 + pos;
            out[idx] = acc[r] + out_b[c] + x[idx];
        }
        if (ct < 3) { WAITV0; SBAR; }
    }
}

// ---------------- launcher ----------------
extern "C" void kernel_launch(void* const* d_in, const int* in_sizes, int n_in,
                              void* d_out, int out_size, void* d_ws, size_t ws_size,
                              hipStream_t stream) {
    (void)in_sizes; (void)n_in; (void)out_size; (void)ws_size;
    const float* x      = (const float*)d_in[0];
    const float* gamma  = (const float*)d_in[1];
    const float* beta   = (const float*)d_in[2];
    const float* qkv_w  = (const float*)d_in[3];
    const float* qkv_b  = (const float*)d_in[4];
    const float* out_w  = (const float*)d_in[5];
    const float* out_b  = (const float*)d_in[6];
    float* out = (float*)d_out;

    char* ws = (char*)d_ws;
    const size_t MB16 = 16777216;
    bf16_t* xn  = (bf16_t*)(ws);             // (b, n, 256) bf16
    bf16_t* qb  = (bf16_t*)(ws + 1 * MB16);  // (b, n, 256)  pre-scaled by QSCALE
    bf16_t* kb  = (bf16_t*)(ws + 2 * MB16);  // (b, n, 256)
    bf16_t* vt  = (bf16_t*)(ws + 3 * MB16);  // (b, 256, n)  V transposed
    bf16_t* ao  = (bf16_t*)(ws + 4 * MB16);  // (b, n, 256)
    bf16_t* wqb = (bf16_t*)(ws + 5 * MB16);            // 768x256 bf16
    bf16_t* wob = (bf16_t*)(ws + 5 * MB16 + 393216);   // 256x256 bf16

    cast_w<<<256, 256, 0, stream>>>(qkv_w, wqb, 196608, out_w, wob, 65536);
    gn_kernel<<<256, 512, 65600, stream>>>(x, gamma, beta, xn);
    gemm_qkv<<<256, 512, 131072, stream>>>(xn, wqb, qkv_b, qb, kb, vt);
    attn_kernel<<<512, 256, 69632, stream>>>(qb, kb, vt, ao);
    gemm_out<<<256, 512, 131072, stream>>>(wob, ao, out_b, x, out);
}

// Round 14
// 121.514 us; speedup vs baseline: 1.0649x; 1.0459x over previous
//
#include <hip/hip_runtime.h>
#include <hip/hip_bf16.h>
#include <stdint.h>

// AttentionBlock: GN(8) -> qkv 1x1 -> attention(1024 tok, d=256) -> proj -> +x
// b=32, c=256, h=w=32 (hw=1024). fp32 in/out; bf16 MFMA internally.

typedef __bf16 bf16_t;
typedef __bf16 bf16x4 __attribute__((ext_vector_type(4)));
typedef __bf16 bf16x8 __attribute__((ext_vector_type(8)));
typedef float f32x16 __attribute__((ext_vector_type(16)));
typedef _Float16 f16x4 __attribute__((ext_vector_type(4)));

#define MFMA32(a, b, c) __builtin_amdgcn_mfma_f32_32x32x16_bf16((a), (b), (c), 0, 0, 0)
#define GLL16(g, l)                                                                      \
    __builtin_amdgcn_global_load_lds((const __attribute__((address_space(1))) void*)(g), \
                                     (__attribute__((address_space(3))) void*)(l), 16, 0, 0)
#define WAITV0 asm volatile("s_waitcnt vmcnt(0)" ::: "memory")
#define SBAR   __builtin_amdgcn_s_barrier()

// Q pre-scale: (1/sqrt(256)) * log2(e)  -> softmax in exp2 domain
#define QSCALE 0.0901684400555f

// ---------------- K1: GroupNorm + transpose (blocks 0-255) + weight casts (>=256) --
__global__ __launch_bounds__(512) void gn_kernel(const float* __restrict__ x,
                                                 const float* __restrict__ gamma,
                                                 const float* __restrict__ beta,
                                                 bf16_t* __restrict__ xn,
                                                 const float* __restrict__ s1,
                                                 bf16_t* __restrict__ d1, int n1,
                                                 const float* __restrict__ s2,
                                                 bf16_t* __restrict__ d2, int n2) {
    if (blockIdx.x >= 256) {  // weight-cast blocks
        int i = (blockIdx.x - 256) * 512 + threadIdx.x;
        int stride = 32 * 512;
        for (int k = i; k < n1; k += stride) d1[k] = (bf16_t)s1[k];
        for (int k = i; k < n2; k += stride) d2[k] = (bf16_t)s2[k];
        return;
    }
    extern __shared__ char gsm[];  // 65536 (fp16 stash) + 64 (reduce)
    float* red = (float*)(gsm + 65536);
    int bg = blockIdx.x, b = bg >> 3, g = bg & 7;
    const float* base = x + (size_t)(b * 256 + g * 32) * 1024;
    int tid = threadIdx.x;
    int half = tid >> 8, col = tid & 255;

    float s = 0.f, ss = 0.f;
    #pragma unroll 4
    for (int c2 = 0; c2 < 16; c2++) {
        int c = c2 * 2 + half;
        float4 v = *(const float4*)(base + c * 1024 + col * 4);
        s += v.x + v.y + v.z + v.w;
        ss += v.x * v.x + v.y * v.y + v.z * v.z + v.w * v.w;
        f16x4 h = {(_Float16)v.x, (_Float16)v.y, (_Float16)v.z, (_Float16)v.w};
        *(f16x4*)(gsm + c * 2048 + ((col * 8) ^ ((c & 7) << 4))) = h;
    }
    for (int off = 32; off; off >>= 1) { s += __shfl_down(s, off); ss += __shfl_down(ss, off); }
    if ((tid & 63) == 0) { red[tid >> 6] = s; red[8 + (tid >> 6)] = ss; }
    __syncthreads();
    float S = 0.f, SS = 0.f;
    #pragma unroll
    for (int k = 0; k < 8; k++) { S += red[k]; SS += red[8 + k]; }
    float mean = S * (1.0f / 32768.0f);
    float var = SS * (1.0f / 32768.0f) - mean * mean;
    float rstd = rsqrtf(var + 1e-5f);

    int c = tid & 31;
    float gam = gamma[g * 32 + c] * rstd;
    float bet = beta[g * 32 + c] - mean * gam;
    bf16_t* dst = xn + (size_t)(b * 1024) * 256 + g * 32 + c;
    #pragma unroll 4
    for (int it = 0; it < 64; it++) {
        int p = it * 16 + (tid >> 5);
        _Float16 hv = *(_Float16*)(gsm + c * 2048 + ((p * 2) ^ ((c & 7) << 4)));
        dst[(size_t)p * 256] = (bf16_t)((float)hv * gam + bet);
    }
}

// ---------------- K2: merged QKV GEMM — 512 threads, 8 wave-tiles of 32x32 --------
__global__ __launch_bounds__(512, 2) void gemm_qkv(const bf16_t* __restrict__ xn,
                                                   const bf16_t* __restrict__ wq,
                                                   const float* __restrict__ qkv_b,
                                                   bf16_t* __restrict__ qb,
                                                   bf16_t* __restrict__ kb,
                                                   bf16_t* __restrict__ vt) {
    extern __shared__ char smem[];  // As 64KB | B dbuf 2x32KB
    char* As = smem;
    int tid = threadIdx.x, wv = tid >> 6, lane = tid & 63;
    int l31 = lane & 31, hi = lane >> 5;
    int t0 = blockIdx.x * 128;
    const char* asrc = (const char*)xn + (size_t)t0 * 512;
    const char* wsrc = (const char*)wq;

    {
        int u = lane & 31, rofs = lane >> 5;
        #pragma unroll
        for (int t = 0; t < 8; t++) {
            int r0 = wv * 16 + t * 2;
            int r = r0 + rofs;
            GLL16(asrc + (size_t)r * 512 + ((u ^ (r & 31)) * 16), As + r0 * 512);
        }
    }
    auto stage_B = [&](int nt) {
        char* Bd = smem + 65536 + (nt & 1) * 32768;
        int u = lane & 31, rofs = lane >> 5;
        #pragma unroll
        for (int t = 0; t < 4; t++) {
            int r0 = wv * 8 + t * 2;
            int r = r0 + rofs;
            GLL16(wsrc + (size_t)(nt * 64 + r) * 512 + ((u ^ (r & 31)) * 16), Bd + r0 * 512);
        }
    };
    stage_B(0);
    WAITV0; SBAR;

    int wm = wv >> 1, wd = wv & 1;
    int bb = t0 >> 10, pos0 = t0 & 1023;

    for (int nt = 0; nt < 12; nt++) {
        if (nt < 11) stage_B(nt + 1);
        const char* Bs = smem + 65536 + (nt & 1) * 32768;
        f32x16 acc = {};
        if (nt < 8) {
            __builtin_amdgcn_s_setprio(1);
            #pragma unroll
            for (int ks = 0; ks < 16; ks++) {
                int col = ks * 32 + hi * 16;
                bf16x8 a = *(const bf16x8*)(As + (wm * 32 + l31) * 512 + (col ^ (l31 << 4)));
                bf16x8 bfr = *(const bf16x8*)(Bs + (wd * 32 + l31) * 512 + (col ^ (l31 << 4)));
                acc = MFMA32(a, bfr, acc);
            }
            __builtin_amdgcn_s_setprio(0);
            int d = nt * 64 + wd * 32 + l31;
            bool isq = nt < 4;
            float bias = qkv_b[d];
            bf16_t* dst = isq ? qb : kb;
            int dd = isq ? d : d - 256;
            float sc = isq ? QSCALE : 1.0f;
            #pragma unroll
            for (int r = 0; r < 16; r++) {
                int tok = t0 + wm * 32 + (r & 3) + 8 * (r >> 2) + 4 * hi;
                dst[(size_t)tok * 256 + dd] = (bf16_t)((acc[r] + bias) * sc);
            }
        } else {
            __builtin_amdgcn_s_setprio(1);
            #pragma unroll
            for (int ks = 0; ks < 16; ks++) {
                int col = ks * 32 + hi * 16;
                bf16x8 a = *(const bf16x8*)(As + (wm * 32 + l31) * 512 + (col ^ (l31 << 4)));
                bf16x8 bfr = *(const bf16x8*)(Bs + (wd * 32 + l31) * 512 + (col ^ (l31 << 4)));
                acc = MFMA32(bfr, a, acc);  // swapped: D[d][tok]
            }
            __builtin_amdgcn_s_setprio(0);
            int dbase = (nt - 8) * 64 + wd * 32;
            int pos = pos0 + wm * 32 + l31;
            #pragma unroll
            for (int r = 0; r < 16; r++) {
                int d = dbase + (r & 3) + 8 * (r >> 2) + 4 * hi;
                vt[(size_t)bb * 262144 + (size_t)d * 1024 + pos] =
                    (bf16_t)(acc[r] + qkv_b[512 + d]);
            }
        }
        if (nt < 11) { WAITV0; SBAR; }
    }
}

// ---------------- K3: fused attention — R11 structure, improved V swizzle ---------
// 256 blocks (1/CU), 4 waves x 32 q-rows (Tq=128), Tk=64, full-d o[8]/wave.
// LDS-P (per-wave 4KB), ONE __syncthreads per chunk, stage-at-top overlap.
// K: 512B rows, 5-bit XOR key (r&31) — 2-way. V: 2 half-buffers of 256x64B rows,
// key (d>>1)&3 on addr bits 4-5 (from unflipped bits 7-8; involution) — 2-way.
__global__ __launch_bounds__(256, 1) void attn_kernel(const bf16_t* __restrict__ qb,
                                                      const bf16_t* __restrict__ kb,
                                                      const bf16_t* __restrict__ vt,
                                                      bf16_t* __restrict__ ao) {
    extern __shared__ char smem[];  // K dbuf 2x32KB | V dbuf 2x32KB @65536 | P 16KB @131072
    int tid = threadIdx.x, i = blockIdx.x;
    int b = (i & 7) + ((i >> 6) << 3);
    int qt = (i >> 3) & 7;
    int wv = tid >> 6, lane = tid & 63, l31 = lane & 31, hi = lane >> 5;

    const char* kbase = (const char*)kb + (size_t)b * 524288;
    const char* vbase = (const char*)vt + (size_t)b * 524288;
    char* Pw = smem + 131072 + wv * 4096;

    int qg = qt * 128 + wv * 32 + l31;
    const char* qsrc = (const char*)qb + (size_t)(b * 1024 + qg) * 512;
    bf16x8 qf[16];
    #pragma unroll
    for (int ks = 0; ks < 16; ks++) qf[ks] = *(const bf16x8*)(qsrc + ks * 32 + hi * 16);

    f32x16 o[8] = {};
    float mrun = -1e30f, lrun = 0.f;

    // stage chunk ch (64 keys) into buffer ch&1
    auto stage = [&](int ch) {
        char* Kd = smem + (ch & 1) * 32768;
        char* Vd = smem + 65536 + (ch & 1) * 32768;
        int j0 = ch * 64;
        #pragma unroll
        for (int t = 0; t < 8; t++) {  // K: 64 rows x 512B, key r&31
            int r0 = wv * 16 + t * 2;
            int r = r0 + (lane >> 5), u = lane & 31;
            GLL16(kbase + (size_t)(j0 + r) * 512 + ((u ^ (r & 31)) * 16), Kd + r0 * 512);
        }
        #pragma unroll
        for (int h = 0; h < 2; h++) {  // V: 2 halves x (256 d-rows x 64B), key (d>>1)&3
            #pragma unroll
            for (int p = 0; p < 4; p++) {
                int Ls = (tid << 4) + (p << 12);
                int s = Ls ^ (((Ls >> 7) & 3) << 4);
                GLL16(vbase + (size_t)(s >> 6) * 2048 + j0 * 2 + h * 64 + (s & 63),
                      Vd + h * 16384 + (p << 12) + wv * 1024);
            }
        }
    };

    stage(0);
    __syncthreads();

    for (int ch = 0; ch < 16; ch++) {
        const char* Ks = smem + (ch & 1) * 32768;
        const char* Vs = smem + 65536 + (ch & 1) * 32768;
        if (ch < 15) stage(ch + 1);

        // S^T = K Q^T : two 32-key tiles, q = l31 in-lane
        f32x16 sv0 = {}, sv1 = {};
        #pragma unroll
        for (int ks = 0; ks < 16; ks++) {
            int col = ks * 32 + hi * 16;
            bf16x8 k0 = *(const bf16x8*)(Ks + l31 * 512 + (col ^ (l31 << 4)));
            bf16x8 k1 = *(const bf16x8*)(Ks + (32 + l31) * 512 + (col ^ (l31 << 4)));
            sv0 = MFMA32(k0, qf[ks], sv0);
            sv1 = MFMA32(k1, qf[ks], sv1);
        }

        // online softmax, exp2 domain, defer-max THR=8
        float mc = -1e30f;
        #pragma unroll
        for (int r = 0; r < 16; r++) mc = fmaxf(mc, fmaxf(sv0[r], sv1[r]));
        mc = fmaxf(mc, __shfl_xor(mc, 32));
        float mo = mrun;
        float mn = (mc <= mo + 8.0f) ? mo : mc;
        float rs = 0.f;
        #pragma unroll
        for (int r = 0; r < 16; r++) {
            sv0[r] = exp2f(sv0[r] - mn);
            sv1[r] = exp2f(sv1[r] - mn);
            rs += sv0[r] + sv1[r];
        }
        rs += __shfl_xor(rs, 32);
        float al = exp2f(mo - mn);
        lrun = lrun * al + rs;
        mrun = mn;

        // P -> LDS: row q=l31 (128B), swizzled (2-way free)
        #pragma unroll
        for (int rg = 0; rg < 4; rg++) {
            bf16x4 pa, pb;
            #pragma unroll
            for (int r = 0; r < 4; r++) {
                pa[r] = (bf16_t)sv0[rg * 4 + r];
                pb[r] = (bf16_t)sv1[rg * 4 + r];
            }
            int sw = (l31 & 7) << 4;
            *(bf16x4*)(Pw + l31 * 128 + ((rg * 16 + hi * 8) ^ sw)) = pa;
            *(bf16x4*)(Pw + l31 * 128 + ((64 + rg * 16 + hi * 8) ^ sw)) = pb;
        }
        if (__any(mn != mo)) {
            #pragma unroll
            for (int dt = 0; dt < 8; dt++) o[dt] = o[dt] * al;
        }

        // O^T += V^T P^T : A = V^T rows (d, key (d>>1)&3), B = P cols (q)
        #pragma unroll
        for (int pk = 0; pk < 4; pk++) {
            int pcol = (pk * 32 + hi * 16) ^ ((l31 & 7) << 4);
            bf16x8 pf = *(const bf16x8*)(Pw + l31 * 128 + pcol);
            const char* Vh = Vs + (pk >> 1) * 16384;
            #pragma unroll
            for (int dt = 0; dt < 8; dt++) {
                int d = dt * 32 + l31;
                int a = (d * 64 + (pk & 1) * 32 + hi * 16) ^ (((d >> 1) & 3) << 4);
                bf16x8 vf = *(const bf16x8*)(Vh + a);
                o[dt] = MFMA32(vf, pf, o[dt]);
            }
        }
        __syncthreads();  // drains vmcnt (stage ch+1 done) + all reads of cur finished
    }

    float inv = 1.0f / lrun;
    char* aod = (char*)ao + (size_t)(b * 1024 + qg) * 512;
    #pragma unroll
    for (int dt = 0; dt < 8; dt++) {
        #pragma unroll
        for (int rg = 0; rg < 4; rg++) {
            bf16x4 w;
            #pragma unroll
            for (int r = 0; r < 4; r++) w[r] = (bf16_t)(o[dt][rg * 4 + r] * inv);
            *(bf16x4*)(aod + dt * 64 + rg * 16 + hi * 8) = w;
        }
    }
}

// ---------------- K4: out-proj GEMM + bias + residual — 512 threads ---------------
__global__ __launch_bounds__(512, 2) void gemm_out(const bf16_t* __restrict__ wo,
                                                   const bf16_t* __restrict__ ao,
                                                   const float* __restrict__ out_b,
                                                   const float* __restrict__ x,
                                                   float* __restrict__ out) {
    extern __shared__ char smem[];  // Bs(ao) 64KB | W dbuf 2x32KB
    char* Bs = smem;
    int tid = threadIdx.x, wv = tid >> 6, lane = tid & 63;
    int l31 = lane & 31, hi = lane >> 5;
    int t0 = blockIdx.x * 128;
    const char* bsrc = (const char*)ao + (size_t)t0 * 512;
    const char* wsrc = (const char*)wo;

    {
        int u = lane & 31, rofs = lane >> 5;
        #pragma unroll
        for (int t = 0; t < 8; t++) {
            int r0 = wv * 16 + t * 2;
            int r = r0 + rofs;
            GLL16(bsrc + (size_t)r * 512 + ((u ^ (r & 31)) * 16), Bs + r0 * 512);
        }
    }
    auto stage_W = [&](int ct) {
        char* Wd = smem + 65536 + (ct & 1) * 32768;
        int u = lane & 31, rofs = lane >> 5;
        #pragma unroll
        for (int t = 0; t < 4; t++) {
            int r0 = wv * 8 + t * 2;
            int r = r0 + rofs;
            GLL16(wsrc + (size_t)(ct * 64 + r) * 512 + ((u ^ (r & 31)) * 16), Wd + r0 * 512);
        }
    };
    stage_W(0);
    WAITV0; SBAR;

    int wm = wv >> 1, wc = wv & 1;
    int bb = t0 >> 10, pos0 = t0 & 1023;

    for (int ct = 0; ct < 4; ct++) {
        if (ct < 3) stage_W(ct + 1);
        const char* Ws = smem + 65536 + (ct & 1) * 32768;
        f32x16 acc = {};
        __builtin_amdgcn_s_setprio(1);
        #pragma unroll
        for (int ks = 0; ks < 16; ks++) {
            int col = ks * 32 + hi * 16;
            bf16x8 w = *(const bf16x8*)(Ws + (wc * 32 + l31) * 512 + (col ^ (l31 << 4)));
            bf16x8 bf = *(const bf16x8*)(Bs + (wm * 32 + l31) * 512 + (col ^ (l31 << 4)));
            acc = MFMA32(w, bf, acc);
        }
        __builtin_amdgcn_s_setprio(0);
        int pos = pos0 + wm * 32 + l31;
        #pragma unroll
        for (int r = 0; r < 16; r++) {
            int c = ct * 64 + wc * 32 + (r & 3) + 8 * (r >> 2) + 4 * hi;
            size_t idx = ((size_t)bb * 256 + c) * 1024 + pos;
            out[idx] = acc[r] + out_b[c] + x[idx];
        }
        if (ct < 3) { WAITV0; SBAR; }
    }
}

// ---------------- launcher ----------------
extern "C" void kernel_launch(void* const* d_in, const int* in_sizes, int n_in,
                              void* d_out, int out_size, void* d_ws, size_t ws_size,
                              hipStream_t stream) {
    (void)in_sizes; (void)n_in; (void)out_size; (void)ws_size;
    const float* x      = (const float*)d_in[0];
    const float* gamma  = (const float*)d_in[1];
    const float* beta   = (const float*)d_in[2];
    const float* qkv_w  = (const float*)d_in[3];
    const float* qkv_b  = (const float*)d_in[4];
    const float* out_w  = (const float*)d_in[5];
    const float* out_b  = (const float*)d_in[6];
    float* out = (float*)d_out;

    char* ws = (char*)d_ws;
    const size_t MB16 = 16777216;
    bf16_t* xn  = (bf16_t*)(ws);             // (b, n, 256) bf16
    bf16_t* qb  = (bf16_t*)(ws + 1 * MB16);  // (b, n, 256)  pre-scaled by QSCALE
    bf16_t* kb  = (bf16_t*)(ws + 2 * MB16);  // (b, n, 256)
    bf16_t* vt  = (bf16_t*)(ws + 3 * MB16);  // (b, 256, n)  V transposed
    bf16_t* ao  = (bf16_t*)(ws + 4 * MB16);  // (b, n, 256)
    bf16_t* wqb = (bf16_t*)(ws + 5 * MB16);            // 768x256 bf16
    bf16_t* wob = (bf16_t*)(ws + 5 * MB16 + 393216);   // 256x256 bf16

    gn_kernel<<<288, 512, 65600, stream>>>(x, gamma, beta, xn,
                                           qkv_w, wqb, 196608, out_w, wob, 65536);
    gemm_qkv<<<256, 512, 131072, stream>>>(xn, wqb, qkv_b, qb, kb, vt);
    attn_kernel<<<256, 256, 147456, stream>>>(qb, kb, vt, ao);
    gemm_out<<<256, 512, 131072, stream>>>(wob, ao, out_b, x, out);
}

// Round 15
// 120.600 us; speedup vs baseline: 1.0730x; 1.0076x over previous
//
#include <hip/hip_runtime.h>
#include <hip/hip_bf16.h>
#include <stdint.h>

// AttentionBlock: GN(8) -> qkv 1x1 -> attention(1024 tok, d=256) -> proj -> +x
// b=32, c=256, h=w=32 (hw=1024). fp32 in/out; bf16 MFMA internally.

typedef __bf16 bf16_t;
typedef __bf16 bf16x4 __attribute__((ext_vector_type(4)));
typedef __bf16 bf16x8 __attribute__((ext_vector_type(8)));
typedef float f32x16 __attribute__((ext_vector_type(16)));
typedef _Float16 f16x4 __attribute__((ext_vector_type(4)));

#define MFMA32(a, b, c) __builtin_amdgcn_mfma_f32_32x32x16_bf16((a), (b), (c), 0, 0, 0)
#define GLL16(g, l)                                                                      \
    __builtin_amdgcn_global_load_lds((const __attribute__((address_space(1))) void*)(g), \
                                     (__attribute__((address_space(3))) void*)(l), 16, 0, 0)
#define WAITV0 asm volatile("s_waitcnt vmcnt(0)" ::: "memory")
#define SBAR   __builtin_amdgcn_s_barrier()

// Q pre-scale: (1/sqrt(256)) * log2(e)  -> softmax in exp2 domain
#define QSCALE 0.0901684400555f

// ---------------- K1: GroupNorm + transpose (blocks 0-255) + weight casts (>=256) --
__global__ __launch_bounds__(512) void gn_kernel(const float* __restrict__ x,
                                                 const float* __restrict__ gamma,
                                                 const float* __restrict__ beta,
                                                 bf16_t* __restrict__ xn,
                                                 const float* __restrict__ s1,
                                                 bf16_t* __restrict__ d1, int n1,
                                                 const float* __restrict__ s2,
                                                 bf16_t* __restrict__ d2, int n2) {
    if (blockIdx.x >= 256) {  // weight-cast blocks
        int i = (blockIdx.x - 256) * 512 + threadIdx.x;
        int stride = 32 * 512;
        for (int k = i; k < n1; k += stride) d1[k] = (bf16_t)s1[k];
        for (int k = i; k < n2; k += stride) d2[k] = (bf16_t)s2[k];
        return;
    }
    extern __shared__ char gsm[];  // 65536 (fp16 stash) + 64 (reduce)
    float* red = (float*)(gsm + 65536);
    int bg = blockIdx.x, b = bg >> 3, g = bg & 7;
    const float* base = x + (size_t)(b * 256 + g * 32) * 1024;
    int tid = threadIdx.x;
    int half = tid >> 8, col = tid & 255;

    float s = 0.f, ss = 0.f;
    #pragma unroll 4
    for (int c2 = 0; c2 < 16; c2++) {
        int c = c2 * 2 + half;
        float4 v = *(const float4*)(base + c * 1024 + col * 4);
        s += v.x + v.y + v.z + v.w;
        ss += v.x * v.x + v.y * v.y + v.z * v.z + v.w * v.w;
        f16x4 h = {(_Float16)v.x, (_Float16)v.y, (_Float16)v.z, (_Float16)v.w};
        *(f16x4*)(gsm + c * 2048 + ((col * 8) ^ ((c & 7) << 4))) = h;
    }
    for (int off = 32; off; off >>= 1) { s += __shfl_down(s, off); ss += __shfl_down(ss, off); }
    if ((tid & 63) == 0) { red[tid >> 6] = s; red[8 + (tid >> 6)] = ss; }
    __syncthreads();
    float S = 0.f, SS = 0.f;
    #pragma unroll
    for (int k = 0; k < 8; k++) { S += red[k]; SS += red[8 + k]; }
    float mean = S * (1.0f / 32768.0f);
    float var = SS * (1.0f / 32768.0f) - mean * mean;
    float rstd = rsqrtf(var + 1e-5f);

    int c = tid & 31;
    float gam = gamma[g * 32 + c] * rstd;
    float bet = beta[g * 32 + c] - mean * gam;
    bf16_t* dst = xn + (size_t)(b * 1024) * 256 + g * 32 + c;
    #pragma unroll 4
    for (int it = 0; it < 64; it++) {
        int p = it * 16 + (tid >> 5);
        _Float16 hv = *(_Float16*)(gsm + c * 2048 + ((p * 2) ^ ((c & 7) << 4)));
        dst[(size_t)p * 256] = (bf16_t)((float)hv * gam + bet);
    }
}

// ---------------- K2: merged QKV GEMM — 512 threads, 8 wave-tiles of 32x32 --------
__global__ __launch_bounds__(512, 2) void gemm_qkv(const bf16_t* __restrict__ xn,
                                                   const bf16_t* __restrict__ wq,
                                                   const float* __restrict__ qkv_b,
                                                   bf16_t* __restrict__ qb,
                                                   bf16_t* __restrict__ kb,
                                                   bf16_t* __restrict__ vt) {
    extern __shared__ char smem[];  // As 64KB | B dbuf 2x32KB
    char* As = smem;
    int tid = threadIdx.x, wv = tid >> 6, lane = tid & 63;
    int l31 = lane & 31, hi = lane >> 5;
    int t0 = blockIdx.x * 128;
    const char* asrc = (const char*)xn + (size_t)t0 * 512;
    const char* wsrc = (const char*)wq;

    {
        int u = lane & 31, rofs = lane >> 5;
        #pragma unroll
        for (int t = 0; t < 8; t++) {
            int r0 = wv * 16 + t * 2;
            int r = r0 + rofs;
            GLL16(asrc + (size_t)r * 512 + ((u ^ (r & 31)) * 16), As + r0 * 512);
        }
    }
    auto stage_B = [&](int nt) {
        char* Bd = smem + 65536 + (nt & 1) * 32768;
        int u = lane & 31, rofs = lane >> 5;
        #pragma unroll
        for (int t = 0; t < 4; t++) {
            int r0 = wv * 8 + t * 2;
            int r = r0 + rofs;
            GLL16(wsrc + (size_t)(nt * 64 + r) * 512 + ((u ^ (r & 31)) * 16), Bd + r0 * 512);
        }
    };
    stage_B(0);
    WAITV0; SBAR;

    int wm = wv >> 1, wd = wv & 1;
    int bb = t0 >> 10, pos0 = t0 & 1023;

    for (int nt = 0; nt < 12; nt++) {
        if (nt < 11) stage_B(nt + 1);
        const char* Bs = smem + 65536 + (nt & 1) * 32768;
        f32x16 acc = {};
        if (nt < 8) {
            __builtin_amdgcn_s_setprio(1);
            #pragma unroll
            for (int ks = 0; ks < 16; ks++) {
                int col = ks * 32 + hi * 16;
                bf16x8 a = *(const bf16x8*)(As + (wm * 32 + l31) * 512 + (col ^ (l31 << 4)));
                bf16x8 bfr = *(const bf16x8*)(Bs + (wd * 32 + l31) * 512 + (col ^ (l31 << 4)));
                acc = MFMA32(a, bfr, acc);
            }
            __builtin_amdgcn_s_setprio(0);
            int d = nt * 64 + wd * 32 + l31;
            bool isq = nt < 4;
            float bias = qkv_b[d];
            bf16_t* dst = isq ? qb : kb;
            int dd = isq ? d : d - 256;
            float sc = isq ? QSCALE : 1.0f;
            #pragma unroll
            for (int r = 0; r < 16; r++) {
                int tok = t0 + wm * 32 + (r & 3) + 8 * (r >> 2) + 4 * hi;
                dst[(size_t)tok * 256 + dd] = (bf16_t)((acc[r] + bias) * sc);
            }
        } else {
            __builtin_amdgcn_s_setprio(1);
            #pragma unroll
            for (int ks = 0; ks < 16; ks++) {
                int col = ks * 32 + hi * 16;
                bf16x8 a = *(const bf16x8*)(As + (wm * 32 + l31) * 512 + (col ^ (l31 << 4)));
                bf16x8 bfr = *(const bf16x8*)(Bs + (wd * 32 + l31) * 512 + (col ^ (l31 << 4)));
                acc = MFMA32(bfr, a, acc);  // swapped: D[d][tok]
            }
            __builtin_amdgcn_s_setprio(0);
            int dbase = (nt - 8) * 64 + wd * 32;
            int pos = pos0 + wm * 32 + l31;
            #pragma unroll
            for (int r = 0; r < 16; r++) {
                int d = dbase + (r & 3) + 8 * (r >> 2) + 4 * hi;
                vt[(size_t)bb * 262144 + (size_t)d * 1024 + pos] =
                    (bf16_t)(acc[r] + qkv_b[512 + d]);
            }
        }
        if (nt < 11) { WAITV0; SBAR; }
    }
}

// ---------------- K3: fused attention — R14 structure, K-early / V-late prefetch ---
// 256 blocks (1/CU), 4 waves x 32 q-rows (Tq=128), Tk=64, full-d o[8]/wave.
// LDS-P (per-wave 4KB), ONE __syncthreads per chunk. K(ch+1) staged before QKT
// (max latency budget); V(ch+1) staged after QKT (addr-calc off the MFMA path).
__global__ __launch_bounds__(256, 1) void attn_kernel(const bf16_t* __restrict__ qb,
                                                      const bf16_t* __restrict__ kb,
                                                      const bf16_t* __restrict__ vt,
                                                      bf16_t* __restrict__ ao) {
    extern __shared__ char smem[];  // K dbuf 2x32KB | V dbuf 2x32KB @65536 | P 16KB @131072
    int tid = threadIdx.x, i = blockIdx.x;
    int b = (i & 7) + ((i >> 6) << 3);
    int qt = (i >> 3) & 7;
    int wv = tid >> 6, lane = tid & 63, l31 = lane & 31, hi = lane >> 5;

    const char* kbase = (const char*)kb + (size_t)b * 524288;
    const char* vbase = (const char*)vt + (size_t)b * 524288;
    char* Pw = smem + 131072 + wv * 4096;

    int qg = qt * 128 + wv * 32 + l31;
    const char* qsrc = (const char*)qb + (size_t)(b * 1024 + qg) * 512;
    bf16x8 qf[16];
    #pragma unroll
    for (int ks = 0; ks < 16; ks++) qf[ks] = *(const bf16x8*)(qsrc + ks * 32 + hi * 16);

    f32x16 o[8] = {};
    float mrun = -1e30f, lrun = 0.f;

    auto stage_K = [&](int ch) {
        char* Kd = smem + (ch & 1) * 32768;
        int j0 = ch * 64;
        #pragma unroll
        for (int t = 0; t < 8; t++) {  // K: 64 rows x 512B, key r&31
            int r0 = wv * 16 + t * 2;
            int r = r0 + (lane >> 5), u = lane & 31;
            GLL16(kbase + (size_t)(j0 + r) * 512 + ((u ^ (r & 31)) * 16), Kd + r0 * 512);
        }
    };
    auto stage_V = [&](int ch) {
        char* Vd = smem + 65536 + (ch & 1) * 32768;
        int j0 = ch * 64;
        #pragma unroll
        for (int h = 0; h < 2; h++) {  // V: 2 halves x (256 d-rows x 64B), key (d>>1)&3
            #pragma unroll
            for (int p = 0; p < 4; p++) {
                int Ls = (tid << 4) + (p << 12);
                int s = Ls ^ (((Ls >> 7) & 3) << 4);
                GLL16(vbase + (size_t)(s >> 6) * 2048 + j0 * 2 + h * 64 + (s & 63),
                      Vd + h * 16384 + (p << 12) + wv * 1024);
            }
        }
    };

    stage_K(0);
    stage_V(0);
    __syncthreads();

    for (int ch = 0; ch < 16; ch++) {
        const char* Ks = smem + (ch & 1) * 32768;
        const char* Vs = smem + 65536 + (ch & 1) * 32768;
        if (ch < 15) stage_K(ch + 1);

        // S^T = K Q^T : two 32-key tiles, q = l31 in-lane
        f32x16 sv0 = {}, sv1 = {};
        #pragma unroll
        for (int ks = 0; ks < 16; ks++) {
            int col = ks * 32 + hi * 16;
            bf16x8 k0 = *(const bf16x8*)(Ks + l31 * 512 + (col ^ (l31 << 4)));
            bf16x8 k1 = *(const bf16x8*)(Ks + (32 + l31) * 512 + (col ^ (l31 << 4)));
            sv0 = MFMA32(k0, qf[ks], sv0);
            sv1 = MFMA32(k1, qf[ks], sv1);
        }

        if (ch < 15) stage_V(ch + 1);

        // online softmax, exp2 domain, defer-max THR=8
        float mc = -1e30f;
        #pragma unroll
        for (int r = 0; r < 16; r++) mc = fmaxf(mc, fmaxf(sv0[r], sv1[r]));
        mc = fmaxf(mc, __shfl_xor(mc, 32));
        float mo = mrun;
        float mn = (mc <= mo + 8.0f) ? mo : mc;
        float rs = 0.f;
        #pragma unroll
        for (int r = 0; r < 16; r++) {
            sv0[r] = exp2f(sv0[r] - mn);
            sv1[r] = exp2f(sv1[r] - mn);
            rs += sv0[r] + sv1[r];
        }
        rs += __shfl_xor(rs, 32);
        float al = exp2f(mo - mn);
        lrun = lrun * al + rs;
        mrun = mn;

        // P -> LDS: row q=l31 (128B), swizzled
        #pragma unroll
        for (int rg = 0; rg < 4; rg++) {
            bf16x4 pa, pb;
            #pragma unroll
            for (int r = 0; r < 4; r++) {
                pa[r] = (bf16_t)sv0[rg * 4 + r];
                pb[r] = (bf16_t)sv1[rg * 4 + r];
            }
            int sw = (l31 & 7) << 4;
            *(bf16x4*)(Pw + l31 * 128 + ((rg * 16 + hi * 8) ^ sw)) = pa;
            *(bf16x4*)(Pw + l31 * 128 + ((64 + rg * 16 + hi * 8) ^ sw)) = pb;
        }
        if (__any(mn != mo)) {
            #pragma unroll
            for (int dt = 0; dt < 8; dt++) o[dt] = o[dt] * al;
        }

        // O^T += V^T P^T : A = V^T rows (d, key (d>>1)&3), B = P cols (q)
        #pragma unroll
        for (int pk = 0; pk < 4; pk++) {
            int pcol = (pk * 32 + hi * 16) ^ ((l31 & 7) << 4);
            bf16x8 pf = *(const bf16x8*)(Pw + l31 * 128 + pcol);
            const char* Vh = Vs + (pk >> 1) * 16384;
            #pragma unroll
            for (int dt = 0; dt < 8; dt++) {
                int d = dt * 32 + l31;
                int a = (d * 64 + (pk & 1) * 32 + hi * 16) ^ (((d >> 1) & 3) << 4);
                bf16x8 vf = *(const bf16x8*)(Vh + a);
                o[dt] = MFMA32(vf, pf, o[dt]);
            }
        }
        __syncthreads();  // drains vmcnt (stage ch+1 done) + all reads of cur finished
    }

    float inv = 1.0f / lrun;
    char* aod = (char*)ao + (size_t)(b * 1024 + qg) * 512;
    #pragma unroll
    for (int dt = 0; dt < 8; dt++) {
        #pragma unroll
        for (int rg = 0; rg < 4; rg++) {
            bf16x4 w;
            #pragma unroll
            for (int r = 0; r < 4; r++) w[r] = (bf16_t)(o[dt][rg * 4 + r] * inv);
            *(bf16x4*)(aod + dt * 64 + rg * 16 + hi * 8) = w;
        }
    }
}

// ---------------- K4: out-proj GEMM + bias + residual — 512 threads ---------------
__global__ __launch_bounds__(512, 2) void gemm_out(const bf16_t* __restrict__ wo,
                                                   const bf16_t* __restrict__ ao,
                                                   const float* __restrict__ out_b,
                                                   const float* __restrict__ x,
                                                   float* __restrict__ out) {
    extern __shared__ char smem[];  // Bs(ao) 64KB | W dbuf 2x32KB
    char* Bs = smem;
    int tid = threadIdx.x, wv = tid >> 6, lane = tid & 63;
    int l31 = lane & 31, hi = lane >> 5;
    int t0 = blockIdx.x * 128;
    const char* bsrc = (const char*)ao + (size_t)t0 * 512;
    const char* wsrc = (const char*)wo;

    {
        int u = lane & 31, rofs = lane >> 5;
        #pragma unroll
        for (int t = 0; t < 8; t++) {
            int r0 = wv * 16 + t * 2;
            int r = r0 + rofs;
            GLL16(bsrc + (size_t)r * 512 + ((u ^ (r & 31)) * 16), Bs + r0 * 512);
        }
    }
    auto stage_W = [&](int ct) {
        char* Wd = smem + 65536 + (ct & 1) * 32768;
        int u = lane & 31, rofs = lane >> 5;
        #pragma unroll
        for (int t = 0; t < 4; t++) {
            int r0 = wv * 8 + t * 2;
            int r = r0 + rofs;
            GLL16(wsrc + (size_t)(ct * 64 + r) * 512 + ((u ^ (r & 31)) * 16), Wd + r0 * 512);
        }
    };
    stage_W(0);
    WAITV0; SBAR;

    int wm = wv >> 1, wc = wv & 1;
    int bb = t0 >> 10, pos0 = t0 & 1023;

    for (int ct = 0; ct < 4; ct++) {
        if (ct < 3) stage_W(ct + 1);
        const char* Ws = smem + 65536 + (ct & 1) * 32768;
        f32x16 acc = {};
        __builtin_amdgcn_s_setprio(1);
        #pragma unroll
        for (int ks = 0; ks < 16; ks++) {
            int col = ks * 32 + hi * 16;
            bf16x8 w = *(const bf16x8*)(Ws + (wc * 32 + l31) * 512 + (col ^ (l31 << 4)));
            bf16x8 bf = *(const bf16x8*)(Bs + (wm * 32 + l31) * 512 + (col ^ (l31 << 4)));
            acc = MFMA32(w, bf, acc);
        }
        __builtin_amdgcn_s_setprio(0);
        int pos = pos0 + wm * 32 + l31;
        #pragma unroll
        for (int r = 0; r < 16; r++) {
            int c = ct * 64 + wc * 32 + (r & 3) + 8 * (r >> 2) + 4 * hi;
            size_t idx = ((size_t)bb * 256 + c) * 1024 + pos;
            out[idx] = acc[r] + out_b[c] + x[idx];
        }
        if (ct < 3) { WAITV0; SBAR; }
    }
}

// ---------------- launcher ----------------
extern "C" void kernel_launch(void* const* d_in, const int* in_sizes, int n_in,
                              void* d_out, int out_size, void* d_ws, size_t ws_size,
                              hipStream_t stream) {
    (void)in_sizes; (void)n_in; (void)out_size; (void)ws_size;
    const float* x      = (const float*)d_in[0];
    const float* gamma  = (const float*)d_in[1];
    const float* beta   = (const float*)d_in[2];
    const float* qkv_w  = (const float*)d_in[3];
    const float* qkv_b  = (const float*)d_in[4];
    const float* out_w  = (const float*)d_in[5];
    const float* out_b  = (const float*)d_in[6];
    float* out = (float*)d_out;

    char* ws = (char*)d_ws;
    const size_t MB16 = 16777216;
    bf16_t* xn  = (bf16_t*)(ws);             // (b, n, 256) bf16
    bf16_t* qb  = (bf16_t*)(ws + 1 * MB16);  // (b, n, 256)  pre-scaled by QSCALE
    bf16_t* kb  = (bf16_t*)(ws + 2 * MB16);  // (b, n, 256)
    bf16_t* vt  = (bf16_t*)(ws + 3 * MB16);  // (b, 256, n)  V transposed
    bf16_t* ao  = (bf16_t*)(ws + 4 * MB16);  // (b, n, 256)
    bf16_t* wqb = (bf16_t*)(ws + 5 * MB16);            // 768x256 bf16
    bf16_t* wob = (bf16_t*)(ws + 5 * MB16 + 393216);   // 256x256 bf16

    gn_kernel<<<288, 512, 65600, stream>>>(x, gamma, beta, xn,
                                           qkv_w, wqb, 196608, out_w, wob, 65536);
    gemm_qkv<<<256, 512, 131072, stream>>>(xn, wqb, qkv_b, qb, kb, vt);
    attn_kernel<<<256, 256, 147456, stream>>>(qb, kb, vt, ao);
    gemm_out<<<256, 512, 131072, stream>>>(wob, ao, out_b, x, out);
}